// Round 17
// baseline (402.315 us; speedup 1.0000x reference)
//
#include <hip/hip_runtime.h>
#include <math.h>

// ---------------- problem dims ----------------
static constexpr int B_   = 64;
static constexpr int H0_  = 480, W0_ = 80;
static constexpr int C0_  = 8, C1_ = 16, C2_ = 16, C3_ = 32;
static constexpr int H1_  = 160, W1_ = 40;
static constexpr int T_   = 40,  WP_ = 20;
static constexpr int IG_  = 640;
static constexpr int HID_ = 256;
static constexpr int G3_  = 768;
static constexpr int OUT_MAIN_ = B_ * T_ * 2 * HID_;
static constexpr int WSZ_ = G3_ * IG_;  // 491520 elems per dir of W_ih

typedef __attribute__((ext_vector_type(8))) short bf16x8;
typedef __attribute__((ext_vector_type(4))) short s16x4;
typedef __attribute__((ext_vector_type(4))) float f32x4;

__device__ inline short f2bf(float f) {
  unsigned u = __builtin_bit_cast(unsigned, f);
  u = (u + 0x7FFFu + ((u >> 16) & 1u)) >> 16;
  return (short)u;
}
__device__ inline float bf2f(short s) {
  return __builtin_bit_cast(float, ((unsigned)(unsigned short)s) << 16);
}
__device__ inline float sigm_(float x) { return 1.f / (1.f + __expf(-x)); }
__device__ inline float tanh_(float x) { return 1.f - 2.f / (1.f + __expf(2.f * x)); }

__device__ inline void split8(const float* p, bf16x8* hi, bf16x8* lo) {
  float4 u = *(const float4*)p, v = *(const float4*)(p + 4);
  float f[8] = {u.x, u.y, u.z, u.w, v.x, v.y, v.z, v.w};
  bf16x8 h, l;
#pragma unroll
  for (int i = 0; i < 8; ++i) {
    short hs = f2bf(f[i]);
    h[i] = hs;
    l[i] = f2bf(f[i] - bf2f(hs));
  }
  *hi = h; *lo = l;
}

// ======== conv0 (VALU) + conv1 (MFMA) + 3x2 pool, 8 pooled rows/block ====
__global__ __launch_bounds__(512, 4) void conv01_mfma(
    const float* __restrict__ img, const float* __restrict__ w0,
    const float* __restrict__ b0, const float* __restrict__ w1,
    const float* __restrict__ b1, float* __restrict__ y2) {
  __shared__ __align__(16) float im[28 * 88];       // rows 24tb-2..+25, cols -2..85
  __shared__ __align__(16) short y0h[26 * 82 * 8];  // rows 24tb-1..+24, col gc at idx gc+1
  __shared__ __align__(16) short y0l[26 * 82 * 8];
  int b = blockIdx.x / 20, tb = blockIdx.x % 20;
  int tid = threadIdx.x;
  int wave = tid >> 6, lane = tid & 63, q = lane >> 4, m15 = lane & 15;
  const float* imgb = img + (size_t)b * (H0_ * W0_);

  // phase A: stage image band (stride-88 rows; cols 84..87 zeroed)
  for (int i = tid; i < 28 * 88; i += 512) {
    int r = i / 88, col = i % 88;
    int gr = tb * 24 - 2 + r, gc = col - 2;
    float v = 0.f;
    if (gr >= 0 && gr < H0_ && gc >= 0 && gc < W0_) v = imgb[gr * W0_ + gc];
    im[i] = v;
  }
  // conv1 weight fragments: B[k][n], n = m15 = out channel, octet q = tap
  bf16x8 w1hf[3], w1lf[3];
#pragma unroll
  for (int kt = 0; kt < 3; ++kt) {
    int p = kt * 4 + q;
    bf16x8 h, l;
#pragma unroll
    for (int e = 0; e < 8; ++e) {
      float w = (p < 9) ? w1[m15 * 72 + e * 9 + p] : 0.f;
      short hs = f2bf(w);
      h[e] = hs;
      l[e] = f2bf(w - bf2f(hs));
    }
    w1hf[kt] = h; w1lf[kt] = l;
  }
  float b1c = b1[m15];
  __syncthreads();

  // phase B: conv0 -> y0 split-bf16 in LDS; 4 output cols per job.
  {
    int ci = tid & 7;  // constant across grid-stride iterations (512 % 8 == 0)
    float wv0[9];
#pragma unroll
    for (int k = 0; k < 9; ++k) wv0[k] = w0[ci * 9 + k];
    float b0c = b0[ci];
#pragma unroll 1
    for (int i = tid; i < 26 * 21 * 8; i += 512) {
      int rest = i >> 3;
      int g = rest % 21, r = rest / 21;
      int grow = tb * 24 - 1 + r;
      bool rowok = (grow >= 0 && grow < H0_);
      float ra[3][8];
#pragma unroll
      for (int kh = 0; kh < 3; ++kh) {
        float4 u = *(const float4*)&im[(r + kh) * 88 + 4 * g];
        float4 v = *(const float4*)&im[(r + kh) * 88 + 4 * g + 4];
        ra[kh][0] = u.x; ra[kh][1] = u.y; ra[kh][2] = u.z; ra[kh][3] = u.w;
        ra[kh][4] = v.x; ra[kh][5] = v.y; ra[kh][6] = v.z; ra[kh][7] = v.w;
      }
#pragma unroll
      for (int c = 0; c < 4; ++c) {
        int lc = 4 * g + c;
        if (lc < 82) {
          int gc = lc - 1;
          float vv = 0.f;
          if (rowok && gc >= 0 && gc < W0_) {
            float s = b0c;
#pragma unroll
            for (int kh = 0; kh < 3; ++kh)
#pragma unroll
              for (int kw = 0; kw < 3; ++kw)
                s += ra[kh][c + kw] * wv0[kh * 3 + kw];
            vv = fmaxf(s, 0.f);
          }
          short hs = f2bf(vv);
          int di = (r * 82 + lc) * 8 + ci;
          y0h[di] = hs;
          y0l[di] = f2bf(vv - bf2f(hs));
        }
      }
    }
  }
  __syncthreads();

  // phase C: conv1 via MFMA + relu + 3x2 pool; 40 jobs, 5 per wave.
#pragma unroll 1
  for (int j = wave; j < 40; j += 8) {
    int pr = j / 5, ct = j % 5;
    f32x4 pmax = {0.f, 0.f, 0.f, 0.f};  // relu >= 0 so 0-init is safe
#pragma unroll
    for (int rr2 = 0; rr2 < 3; ++rr2) {
      int o = pr * 3 + rr2;  // conv1 local row (global tb*24 + o)
      f32x4 acc = {0.f, 0.f, 0.f, 0.f};
#pragma unroll
      for (int kt = 0; kt < 3; ++kt) {
        int p = kt * 4 + q;
        int pp = (p < 9) ? p : 8;  // pad octets read a valid addr; B is 0 there
        int kh = pp / 3, kw = pp % 3;
        int ar = ((o + kh) * 82 + ct * 16 + m15 + kw) * 8;
        bf16x8 ah = *(const bf16x8*)&y0h[ar];
        bf16x8 al = *(const bf16x8*)&y0l[ar];
        acc = __builtin_amdgcn_mfma_f32_16x16x32_bf16(al, w1hf[kt], acc, 0, 0, 0);
        acc = __builtin_amdgcn_mfma_f32_16x16x32_bf16(ah, w1lf[kt], acc, 0, 0, 0);
        acc = __builtin_amdgcn_mfma_f32_16x16x32_bf16(ah, w1hf[kt], acc, 0, 0, 0);
      }
#pragma unroll
      for (int r = 0; r < 4; ++r)
        pmax[r] = fmaxf(pmax[r], fmaxf(acc[r] + b1c, 0.f));
    }
    int R = tb * 8 + pr;
    size_t base = (((size_t)b * 160 + R) * 40 + ct * 8 + q * 2) * 16 + m15;
    y2[base] = fmaxf(pmax[0], pmax[1]);
    y2[base + 16] = fmaxf(pmax[2], pmax[3]);
  }
}

// ======== conv2 + conv3 + pool via MFMA implicit GEMM, 2 blocks/CU ========
__global__ __launch_bounds__(512, 4) void conv23_mfma(
    const float* __restrict__ y2, const float* __restrict__ w2,
    const float* __restrict__ b2, const float* __restrict__ w3,
    const float* __restrict__ b3, short* __restrict__ xh,
    short* __restrict__ xl) {
  __shared__ __align__(16) short y2h[12 * 42 * 16], y2l[12 * 42 * 16];
  __shared__ __align__(16) short y3h[10 * 42 * 16], y3l[10 * 42 * 16];
  int b = blockIdx.x / 20, tb = blockIdx.x % 20;
  int tid = threadIdx.x;
  int wave = tid >> 6, lane = tid & 63, q = lane >> 4, m15 = lane & 15;
  int ci0 = (q & 1) * 8;

  // phase A: stage y2 band (rows 8tb-2..+9, cols -1..40) as split bf16
  for (int i = tid; i < 12 * 42 * 4; i += 512) {
    int ci4 = i & 3;
    int rest = i >> 2;
    int lc = rest % 42, r = rest / 42;
    int gr = tb * 8 - 2 + r, gc = lc - 1;
    float4 v = {0.f, 0.f, 0.f, 0.f};
    if (gr >= 0 && gr < 160 && gc >= 0 && gc < 40)
      v = *(const float4*)&y2[(((size_t)b * 160 + gr) * 40 + gc) * 16 + ci4 * 4];
    float f[4] = {v.x, v.y, v.z, v.w};
    s16x4 hv, lv;
#pragma unroll
    for (int e = 0; e < 4; ++e) {
      short hs = f2bf(f[e]);
      hv[e] = hs;
      lv[e] = f2bf(f[e] - bf2f(hs));
    }
    int idx = (r * 42 + lc) * 16 + ci4 * 4;
    *(s16x4*)&y2h[idx] = hv;
    *(s16x4*)&y2l[idx] = lv;
  }
  // zero y3 column halos (col 0 and 41, all 10 rows, 16 ch)
  for (int i = tid; i < 10 * 2 * 16; i += 512) {
    int rr = i / 32, sl = i % 32;
    int col = (sl >> 4) * 41, ch = sl & 15;
    y3h[(rr * 42 + col) * 16 + ch] = 0;
    y3l[(rr * 42 + col) * 16 + ch] = 0;
  }
  // conv2 weight fragments: B[k][n], n = m15 = out channel
  bf16x8 w2hf[5], w2lf[5];
#pragma unroll
  for (int kt = 0; kt < 5; ++kt) {
    int p = 2 * kt + (q >> 1);
    bf16x8 h, l;
#pragma unroll
    for (int e = 0; e < 8; ++e) {
      float w = (p < 9) ? w2[(m15 * 16 + ci0 + e) * 9 + p] : 0.f;
      short hs = f2bf(w);
      h[e] = hs;
      l[e] = f2bf(w - bf2f(hs));
    }
    w2hf[kt] = h; w2lf[kt] = l;
  }
  float b2c = b2[m15];
  __syncthreads();

  // phase B: conv2 -> y3 LDS (local rows 0..9 = global 8tb-1..8tb+8)
#pragma unroll 1
  for (int i = wave; i < 30; i += 8) {
    int rr = i / 3, ct = i % 3;
    f32x4 acc = {0.f, 0.f, 0.f, 0.f};
#pragma unroll
    for (int kt = 0; kt < 5; ++kt) {
      int p = 2 * kt + (q >> 1);
      int pp = (p < 9) ? p : 8;  // pad lanes read a valid addr; B is 0 there
      int kh = pp / 3, kw = pp % 3;
      int lc = min(ct * 16 + m15 + kw, 41);
      int ar = ((rr + kh) * 42 + lc) * 16 + ci0;
      bf16x8 ah = *(const bf16x8*)&y2h[ar];
      bf16x8 al = *(const bf16x8*)&y2l[ar];
      acc = __builtin_amdgcn_mfma_f32_16x16x32_bf16(al, w2hf[kt], acc, 0, 0, 0);
      acc = __builtin_amdgcn_mfma_f32_16x16x32_bf16(ah, w2lf[kt], acc, 0, 0, 0);
      acc = __builtin_amdgcn_mfma_f32_16x16x32_bf16(ah, w2hf[kt], acc, 0, 0, 0);
    }
    int grow = tb * 8 - 1 + rr;
    bool rowok = (grow >= 0 && grow < 160);
#pragma unroll
    for (int r = 0; r < 4; ++r) {
      int col = ct * 16 + q * 4 + r;  // C row = pixel col; C col = channel m15
      if (col < 40) {
        float v = rowok ? fmaxf(acc[r] + b2c, 0.f) : 0.f;
        short hs = f2bf(v);
        int di = (rr * 42 + 1 + col) * 16 + m15;
        y3h[di] = hs;
        y3l[di] = f2bf(v - bf2f(hs));
      }
    }
  }
  __syncthreads();

  // conv3 weight fragments: wave -> (pooled row pl, ch half nt, ct parity)
  int pl = wave >> 2, nt = (wave >> 1) & 1, sub = wave & 1;
  bf16x8 w3hf[5], w3lf[5];
#pragma unroll
  for (int kt = 0; kt < 5; ++kt) {
    int p = 2 * kt + (q >> 1);
    bf16x8 h, l;
#pragma unroll
    for (int e = 0; e < 8; ++e) {
      float w = (p < 9) ? w3[((nt * 16 + m15) * 16 + ci0 + e) * 9 + p] : 0.f;
      short hs = f2bf(w);
      h[e] = hs;
      l[e] = f2bf(w - bf2f(hs));
    }
    w3hf[kt] = h; w3lf[kt] = l;
  }
  float b3c = b3[nt * 16 + m15];

  // phase C: conv3 + relu + 4x2 pool, all in registers
#pragma unroll 1
  for (int ct = sub; ct < 3; ct += 2) {
    f32x4 pmax = {0.f, 0.f, 0.f, 0.f};
#pragma unroll
    for (int rr2 = 0; rr2 < 4; ++rr2) {
      int o = pl * 4 + rr2;  // conv3 local row; y3 local rows o..o+2
      f32x4 acc = {0.f, 0.f, 0.f, 0.f};
#pragma unroll
      for (int kt = 0; kt < 5; ++kt) {
        int p = 2 * kt + (q >> 1);
        int pp = (p < 9) ? p : 8;
        int kh = pp / 3, kw = pp % 3;
        int lc = min(ct * 16 + m15 + kw, 41);
        int ar = ((o + kh) * 42 + lc) * 16 + ci0;
        bf16x8 ah = *(const bf16x8*)&y3h[ar];
        bf16x8 al = *(const bf16x8*)&y3l[ar];
        acc = __builtin_amdgcn_mfma_f32_16x16x32_bf16(al, w3hf[kt], acc, 0, 0, 0);
        acc = __builtin_amdgcn_mfma_f32_16x16x32_bf16(ah, w3lf[kt], acc, 0, 0, 0);
        acc = __builtin_amdgcn_mfma_f32_16x16x32_bf16(ah, w3hf[kt], acc, 0, 0, 0);
      }
#pragma unroll
      for (int r = 0; r < 4; ++r) {
        float v = fmaxf(acc[r] + b3c, 0.f);
        pmax[r] = fmaxf(pmax[r], v);
      }
    }
    if (ct < 2 || q < 2) {
      int t = tb * 2 + pl;
      int wo = ct * 8 + q * 2;
      size_t base = (((size_t)t * 64 + b) * 20 + wo) * 32 + nt * 16 + m15;
      float v0 = fmaxf(pmax[0], pmax[1]);
      float v1 = fmaxf(pmax[2], pmax[3]);
      short s0 = f2bf(v0), s1 = f2bf(v1);
      xh[base] = s0;       xl[base] = f2bf(v0 - bf2f(s0));
      xh[base + 32] = s1;  xl[base + 32] = f2bf(v1 - bf2f(s1));
    }
  }
}

// ======== pre-split W_ih into bf16 hi/lo (once, not per gemm block) ========
__global__ __launch_bounds__(256) void split_w(
    const float* __restrict__ wf, const float* __restrict__ wb,
    short* __restrict__ Wh, short* __restrict__ Wl) {
  int i = blockIdx.x * 256 + threadIdx.x;  // octet index, 2*61440 total
  const float* src = (i < 61440) ? (wf + (size_t)i * 8)
                                 : (wb + (size_t)(i - 61440) * 8);
  bf16x8 h, l;
  split8(src, &h, &l);
  *(bf16x8*)&Wh[(size_t)i * 8] = h;
  *(bf16x8*)&Wl[(size_t)i * 8] = l;
}

// ======== gx GEMM: 512 threads (8 waves = 2/SIMD), reg-prefetch dbuf ======
__global__ __launch_bounds__(512, 2) void gemm_gx_mfma(
    const short* __restrict__ xh, const short* __restrict__ xl,
    const short* __restrict__ Wh, const short* __restrict__ Wl,
    const float* __restrict__ bih_f, const float* __restrict__ bih_b,
    const float* __restrict__ bhh_f, const float* __restrict__ bhh_b,
    float* __restrict__ gx) {
  __shared__ __align__(16) short Ah[2][4 * 128 * 8], Al[2][4 * 128 * 8];
  __shared__ __align__(16) short Bh[2][4 * 128 * 8], Bl[2][4 * 128 * 8];
  int bm = blockIdx.x * 128, bn = blockIdx.y * 128, dir = blockIdx.z;
  const short* Whd = Wh + (size_t)dir * WSZ_;
  const short* Wld = Wl + (size_t)dir * WSZ_;
  const float* bias = dir ? bih_b : bih_f;
  const float* bias2 = dir ? bhh_b : bhh_f;
  float* C = gx + (size_t)dir * (T_ * B_) * G3_;
  int tid = threadIdx.x;
  int wave = tid >> 6, lane = tid & 63, q = lane >> 4, n = lane & 15;
  int wm = (wave & 3) * 32, wn2 = (wave >> 2) * 64;
  f32x4 acc[2][4];
#pragma unroll
  for (int mi = 0; mi < 2; ++mi)
#pragma unroll
    for (int ni = 0; ni < 4; ++ni) acc[mi][ni] = (f32x4){0.f, 0.f, 0.f, 0.f};

  // staging map: thread -> (row = tid>>2, k-octet = tid&3)
  int srow = tid >> 2, sko = tid & 3;
  const short* xh0 = &xh[(size_t)(bm + srow) * IG_ + sko * 8];
  const short* xl0 = &xl[(size_t)(bm + srow) * IG_ + sko * 8];
  const short* wh0 = &Whd[(size_t)(bn + srow) * IG_ + sko * 8];
  const short* wl0 = &Wld[(size_t)(bn + srow) * IG_ + sko * 8];
  int sidx = (sko * 128 + srow) * 8;

  // prologue: stage k-tile 0 into buffer 0
  *(bf16x8*)&Ah[0][sidx] = *(const bf16x8*)xh0;
  *(bf16x8*)&Al[0][sidx] = *(const bf16x8*)xl0;
  *(bf16x8*)&Bh[0][sidx] = *(const bf16x8*)wh0;
  *(bf16x8*)&Bl[0][sidx] = *(const bf16x8*)wl0;
  __syncthreads();

  for (int t = 0; t < 20; ++t) {
    int cur = t & 1;
    bf16x8 ra, rl, rb, rm;
    if (t < 19) {
      int ko = (t + 1) * 32;
      ra = *(const bf16x8*)(xh0 + ko); rl = *(const bf16x8*)(xl0 + ko);
      rb = *(const bf16x8*)(wh0 + ko); rm = *(const bf16x8*)(wl0 + ko);
    }
    bf16x8 ah[2], al[2], bh[4], bl[4];
#pragma unroll
    for (int mi = 0; mi < 2; ++mi) {
      ah[mi] = *(const bf16x8*)&Ah[cur][(q * 128 + wm + mi * 16 + n) * 8];
      al[mi] = *(const bf16x8*)&Al[cur][(q * 128 + wm + mi * 16 + n) * 8];
    }
#pragma unroll
    for (int ni = 0; ni < 4; ++ni) {
      bh[ni] = *(const bf16x8*)&Bh[cur][(q * 128 + wn2 + ni * 16 + n) * 8];
      bl[ni] = *(const bf16x8*)&Bl[cur][(q * 128 + wn2 + ni * 16 + n) * 8];
    }
#pragma unroll
    for (int mi = 0; mi < 2; ++mi)
#pragma unroll
      for (int ni = 0; ni < 4; ++ni) {
        acc[mi][ni] = __builtin_amdgcn_mfma_f32_16x16x32_bf16(
            al[mi], bh[ni], acc[mi][ni], 0, 0, 0);
        acc[mi][ni] = __builtin_amdgcn_mfma_f32_16x16x32_bf16(
            ah[mi], bl[ni], acc[mi][ni], 0, 0, 0);
        acc[mi][ni] = __builtin_amdgcn_mfma_f32_16x16x32_bf16(
            ah[mi], bh[ni], acc[mi][ni], 0, 0, 0);
      }
    if (t < 19) {
      int nb = cur ^ 1;
      *(bf16x8*)&Ah[nb][sidx] = ra; *(bf16x8*)&Al[nb][sidx] = rl;
      *(bf16x8*)&Bh[nb][sidx] = rb; *(bf16x8*)&Bl[nb][sidx] = rm;
    }
    __syncthreads();
  }
#pragma unroll
  for (int mi = 0; mi < 2; ++mi)
#pragma unroll
    for (int ni = 0; ni < 4; ++ni)
#pragma unroll
      for (int r = 0; r < 4; ++r) {
        int row = bm + wm + mi * 16 + q * 4 + r;
        int col = bn + wn2 + ni * 16 + n;
        float bb = bias[col] + (col < 512 ? bias2[col] : 0.f);
        C[(size_t)row * G3_ + col] = acc[mi][ni][r] + bb;
      }
}

// ======== weight-stationary MFMA GRU (R8 structure + light barrier) ========
__global__ __launch_bounds__(1024) void gru_mfma(
    const float* __restrict__ gx,
    const float* __restrict__ whh_f, const float* __restrict__ whh_b,
    const float* __restrict__ bhh_f, const float* __restrict__ bhh_b,
    const float* __restrict__ h0, float* __restrict__ out) {
  __shared__ __align__(16) short wn[32 * 256 * 8];    // 128 KB [ch][j][8]
  __shared__ __align__(16) short hb[2][32 * 16 * 8];  // 2x8 KB [ch][b][8]
  int blk = blockIdx.x, dir = blk >> 2, mb = blk & 3;
  const float* Wh  = dir ? whh_b : whh_f;
  const float* bhh = dir ? bhh_b : bhh_f;
  int tid = threadIdx.x;
  int wave = tid >> 6, lane = tid & 63, q = lane >> 4, n = lane & 15;
  int jw = wave << 4;

  for (int idx = tid; idx < 256 * 32; idx += 1024) {
    int j = idx >> 5, ch = idx & 31;
    const float* src = Wh + (size_t)(512 + j) * HID_ + ch * 8;
    float4 u = *(const float4*)src, v = *(const float4*)(src + 4);
    short* d = &wn[(ch * 256 + j) * 8];
    d[0] = f2bf(u.x); d[1] = f2bf(u.y); d[2] = f2bf(u.z); d[3] = f2bf(u.w);
    d[4] = f2bf(v.x); d[5] = f2bf(v.y); d[6] = f2bf(v.z); d[7] = f2bf(v.w);
  }
  if (tid < 512) {
    int b = tid >> 5, ch = tid & 31;
    const float* src = h0 + (size_t)(dir * 64 + mb * 16 + b) * HID_ + ch * 8;
    float4 u = *(const float4*)src, v = *(const float4*)(src + 4);
    short* d = &hb[0][(ch * 16 + b) * 8];
    d[0] = f2bf(u.x); d[1] = f2bf(u.y); d[2] = f2bf(u.z); d[3] = f2bf(u.w);
    d[4] = f2bf(v.x); d[5] = f2bf(v.y); d[6] = f2bf(v.z); d[7] = f2bf(v.w);
  }
  bf16x8 Br[8], Bz[8];
#pragma unroll
  for (int kt = 0; kt < 8; ++kt) {
    const float* pr = Wh + (size_t)(jw + n) * HID_ + kt * 32 + q * 8;
    const float* pz = Wh + (size_t)(256 + jw + n) * HID_ + kt * 32 + q * 8;
    float4 u = *(const float4*)pr, v = *(const float4*)(pr + 4);
    Br[kt] = (bf16x8){f2bf(u.x), f2bf(u.y), f2bf(u.z), f2bf(u.w),
                      f2bf(v.x), f2bf(v.y), f2bf(v.z), f2bf(v.w)};
    float4 uz = *(const float4*)pz, vz = *(const float4*)(pz + 4);
    Bz[kt] = (bf16x8){f2bf(uz.x), f2bf(uz.y), f2bf(uz.z), f2bf(uz.w),
                      f2bf(vz.x), f2bf(vz.y), f2bf(vz.z), f2bf(vz.w)};
  }
  float hold[4];
#pragma unroll
  for (int r = 0; r < 4; ++r)
    hold[r] = h0[(size_t)(dir * 64 + mb * 16 + q * 4 + r) * HID_ + jw + n];
  float bh2 = bhh[512 + jw + n];  // r/z biases folded into gx by gemm
  int chc = (jw + n) >> 3, ce = (jw + n) & 7;

  // preload step 0's gx while weights stage
  float xr[4], xz[4], xn[4];
  {
    int t0 = dir ? (T_ - 1) : 0;
    const float* gxt = gx + ((size_t)(dir * T_ + t0) * B_ + mb * 16) * G3_;
#pragma unroll
    for (int r = 0; r < 4; ++r) {
      const float* gxb = gxt + (size_t)(q * 4 + r) * G3_ + jw + n;
      xr[r] = gxb[0]; xz[r] = gxb[256]; xn[r] = gxb[512];
    }
  }
  __syncthreads();

  for (int s = 0; s < T_; ++s) {
    int t = dir ? (T_ - 1 - s) : s;
    const short* hc = hb[s & 1];
    short* hx = hb[(s & 1) ^ 1];

    // prefetch next step's gx (step-independent data) — issue before MFMAs;
    // properly guarded so the final step issues no wasted loads.
    float pxr[4], pxz[4], pxn[4];
    if (s + 1 < T_) {
      int tn = dir ? (T_ - 2 - s) : s + 1;
      const float* gxt = gx + ((size_t)(dir * T_ + tn) * B_ + mb * 16) * G3_;
#pragma unroll
      for (int r = 0; r < 4; ++r) {
        const float* gxb = gxt + (size_t)(q * 4 + r) * G3_ + jw + n;
        pxr[r] = gxb[0]; pxz[r] = gxb[256]; pxn[r] = gxb[512];
      }
    }

    f32x4 a0 = {0.f, 0.f, 0.f, 0.f}, a1 = a0, a2 = a0;
#pragma unroll
    for (int kt = 0; kt < 8; ++kt) {
      bf16x8 af = *(const bf16x8*)&hc[((kt * 4 + q) * 16 + n) * 8];
      bf16x8 bn = *(const bf16x8*)&wn[((kt * 4 + q) * 256 + jw + n) * 8];
      a0 = __builtin_amdgcn_mfma_f32_16x16x32_bf16(af, Br[kt], a0, 0, 0, 0);
      a1 = __builtin_amdgcn_mfma_f32_16x16x32_bf16(af, Bz[kt], a1, 0, 0, 0);
      a2 = __builtin_amdgcn_mfma_f32_16x16x32_bf16(af, bn, a2, 0, 0, 0);
    }
#pragma unroll
    for (int r = 0; r < 4; ++r) {
      float rg = sigm_(xr[r] + a0[r]);
      float zg = sigm_(xz[r] + a1[r]);
      float ng = tanh_(xn[r] + rg * (a2[r] + bh2));
      float hnew = (1.f - zg) * ng + zg * hold[r];
      hold[r] = hnew;
      int gb = mb * 16 + q * 4 + r;
      out[((size_t)gb * T_ + t) * (2 * HID_) + dir * HID_ + jw + n] = hnew;
      hx[(chc * 16 + q * 4 + r) * 8 + ce] = f2bf(hnew);
    }
    if (s + 1 < T_) {
#pragma unroll
      for (int r = 0; r < 4; ++r) {
        xr[r] = pxr[r]; xz[r] = pxz[r]; xn[r] = pxn[r];
      }
    }
    // light barrier: order LDS hx writes only; leave global stores and the
    // gx prefetch loads in flight (compiler inserts vmcnt at first use).
    asm volatile("s_waitcnt lgkmcnt(0)\n\ts_barrier" ::: "memory");
  }
#pragma unroll
  for (int r = 0; r < 4; ++r)
    out[(size_t)OUT_MAIN_ + (size_t)(dir * 64 + mb * 16 + q * 4 + r) * HID_ + jw + n] = hold[r];
}

// ---------------- launch ----------------
extern "C" void kernel_launch(void* const* d_in, const int* in_sizes, int n_in,
                              void* d_out, int out_size, void* d_ws, size_t ws_size,
                              hipStream_t stream) {
  (void)in_sizes; (void)n_in; (void)out_size; (void)ws_size;
  const float* img    = (const float*)d_in[0];
  const float* hid0   = (const float*)d_in[1];
  const float* c0w    = (const float*)d_in[2];
  const float* c0b    = (const float*)d_in[3];
  const float* c1w    = (const float*)d_in[4];
  const float* c1b    = (const float*)d_in[5];
  const float* c2w    = (const float*)d_in[6];
  const float* c2b    = (const float*)d_in[7];
  const float* c3w    = (const float*)d_in[8];
  const float* c3b    = (const float*)d_in[9];
  const float* wih_f  = (const float*)d_in[10];
  const float* whh_f  = (const float*)d_in[11];
  const float* bih_f  = (const float*)d_in[12];
  const float* bhh_f  = (const float*)d_in[13];
  const float* wih_b  = (const float*)d_in[14];
  const float* whh_b  = (const float*)d_in[15];
  const float* bih_b  = (const float*)d_in[16];
  const float* bhh_b  = (const float*)d_in[17];
  float* out = (float*)d_out;

  float* wsf = (float*)d_ws;
  float* y2  = wsf;                         // 6,553,600 floats (dead after conv23)
  short* xh  = (short*)(wsf + 6553600);     // 1,638,400 shorts
  short* xl  = xh + 1638400;                // 1,638,400 shorts
  float* gx  = wsf + 8192000;               // 3,932,160 floats
  // W splits overlay the y2 region (y2 is dead once conv23 has run;
  // split_w is launched after conv23 because of this aliasing).
  short* Wh  = (short*)wsf;                 // 983,040 shorts
  short* Wl  = Wh + 983040;                 // 983,040 shorts

  conv01_mfma<<<64 * 20, 512, 0, stream>>>(img, c0w, c0b, c1w, c1b, y2);
  conv23_mfma<<<64 * 20, 512, 0, stream>>>(y2, c2w, c2b, c3w, c3b, xh, xl);
  split_w<<<480, 256, 0, stream>>>(wih_f, wih_b, Wh, Wl);
  gemm_gx_mfma<<<dim3(20, 6, 2), 512, 0, stream>>>(xh, xl, Wh, Wl, bih_f, bih_b,
                                                   bhh_f, bhh_b, gx);
  gru_mfma<<<8, 1024, 0, stream>>>(gx, whh_f, whh_b, bhh_f, bhh_b, hid0, out);
}

// Round 18
// 392.514 us; speedup vs baseline: 1.0250x; 1.0250x over previous
//
#include <hip/hip_runtime.h>
#include <math.h>

// ---------------- problem dims ----------------
static constexpr int B_   = 64;
static constexpr int H0_  = 480, W0_ = 80;
static constexpr int C0_  = 8, C1_ = 16, C2_ = 16, C3_ = 32;
static constexpr int H1_  = 160, W1_ = 40;
static constexpr int T_   = 40,  WP_ = 20;
static constexpr int IG_  = 640;
static constexpr int HID_ = 256;
static constexpr int G3_  = 768;
static constexpr int OUT_MAIN_ = B_ * T_ * 2 * HID_;
static constexpr int WSZ_ = G3_ * IG_;  // 491520 elems per dir of W_ih

typedef __attribute__((ext_vector_type(8))) short bf16x8;
typedef __attribute__((ext_vector_type(4))) short s16x4;
typedef __attribute__((ext_vector_type(4))) float f32x4;

__device__ inline short f2bf(float f) {
  unsigned u = __builtin_bit_cast(unsigned, f);
  u = (u + 0x7FFFu + ((u >> 16) & 1u)) >> 16;
  return (short)u;
}
__device__ inline float bf2f(short s) {
  return __builtin_bit_cast(float, ((unsigned)(unsigned short)s) << 16);
}
__device__ inline float sigm_(float x) { return 1.f / (1.f + __expf(-x)); }
__device__ inline float tanh_(float x) { return 1.f - 2.f / (1.f + __expf(2.f * x)); }

__device__ inline void split8(const float* p, bf16x8* hi, bf16x8* lo) {
  float4 u = *(const float4*)p, v = *(const float4*)(p + 4);
  float f[8] = {u.x, u.y, u.z, u.w, v.x, v.y, v.z, v.w};
  bf16x8 h, l;
#pragma unroll
  for (int i = 0; i < 8; ++i) {
    short hs = f2bf(f[i]);
    h[i] = hs;
    l[i] = f2bf(f[i] - bf2f(hs));
  }
  *hi = h; *lo = l;
}

// ======== conv0 (VALU) + conv1 (MFMA) + 3x2 pool, 8 pooled rows/block ====
__global__ __launch_bounds__(512, 4) void conv01_mfma(
    const float* __restrict__ img, const float* __restrict__ w0,
    const float* __restrict__ b0, const float* __restrict__ w1,
    const float* __restrict__ b1, float* __restrict__ y2) {
  __shared__ __align__(16) float im[28 * 88];       // rows 24tb-2..+25, cols -2..85
  __shared__ __align__(16) short y0h[26 * 82 * 8];  // rows 24tb-1..+24, col gc at idx gc+1
  __shared__ __align__(16) short y0l[26 * 82 * 8];
  int b = blockIdx.x / 20, tb = blockIdx.x % 20;
  int tid = threadIdx.x;
  int wave = tid >> 6, lane = tid & 63, q = lane >> 4, m15 = lane & 15;
  const float* imgb = img + (size_t)b * (H0_ * W0_);

  // phase A: stage image band (stride-88 rows; cols 84..87 zeroed)
  for (int i = tid; i < 28 * 88; i += 512) {
    int r = i / 88, col = i % 88;
    int gr = tb * 24 - 2 + r, gc = col - 2;
    float v = 0.f;
    if (gr >= 0 && gr < H0_ && gc >= 0 && gc < W0_) v = imgb[gr * W0_ + gc];
    im[i] = v;
  }
  // conv1 weight fragments: B[k][n], n = m15 = out channel, octet q = tap
  bf16x8 w1hf[3], w1lf[3];
#pragma unroll
  for (int kt = 0; kt < 3; ++kt) {
    int p = kt * 4 + q;
    bf16x8 h, l;
#pragma unroll
    for (int e = 0; e < 8; ++e) {
      float w = (p < 9) ? w1[m15 * 72 + e * 9 + p] : 0.f;
      short hs = f2bf(w);
      h[e] = hs;
      l[e] = f2bf(w - bf2f(hs));
    }
    w1hf[kt] = h; w1lf[kt] = l;
  }
  float b1c = b1[m15];
  __syncthreads();

  // phase B: conv0 -> y0 split-bf16 in LDS; 4 output cols per job.
  {
    int ci = tid & 7;  // constant across grid-stride iterations (512 % 8 == 0)
    float wv0[9];
#pragma unroll
    for (int k = 0; k < 9; ++k) wv0[k] = w0[ci * 9 + k];
    float b0c = b0[ci];
#pragma unroll 1
    for (int i = tid; i < 26 * 21 * 8; i += 512) {
      int rest = i >> 3;
      int g = rest % 21, r = rest / 21;
      int grow = tb * 24 - 1 + r;
      bool rowok = (grow >= 0 && grow < H0_);
      float ra[3][8];
#pragma unroll
      for (int kh = 0; kh < 3; ++kh) {
        float4 u = *(const float4*)&im[(r + kh) * 88 + 4 * g];
        float4 v = *(const float4*)&im[(r + kh) * 88 + 4 * g + 4];
        ra[kh][0] = u.x; ra[kh][1] = u.y; ra[kh][2] = u.z; ra[kh][3] = u.w;
        ra[kh][4] = v.x; ra[kh][5] = v.y; ra[kh][6] = v.z; ra[kh][7] = v.w;
      }
#pragma unroll
      for (int c = 0; c < 4; ++c) {
        int lc = 4 * g + c;
        if (lc < 82) {
          int gc = lc - 1;
          float vv = 0.f;
          if (rowok && gc >= 0 && gc < W0_) {
            float s = b0c;
#pragma unroll
            for (int kh = 0; kh < 3; ++kh)
#pragma unroll
              for (int kw = 0; kw < 3; ++kw)
                s += ra[kh][c + kw] * wv0[kh * 3 + kw];
            vv = fmaxf(s, 0.f);
          }
          short hs = f2bf(vv);
          int di = (r * 82 + lc) * 8 + ci;
          y0h[di] = hs;
          y0l[di] = f2bf(vv - bf2f(hs));
        }
      }
    }
  }
  __syncthreads();

  // phase C: conv1 via MFMA + relu + 3x2 pool; 40 jobs, 5 per wave.
#pragma unroll 1
  for (int j = wave; j < 40; j += 8) {
    int pr = j / 5, ct = j % 5;
    f32x4 pmax = {0.f, 0.f, 0.f, 0.f};  // relu >= 0 so 0-init is safe
#pragma unroll
    for (int rr2 = 0; rr2 < 3; ++rr2) {
      int o = pr * 3 + rr2;  // conv1 local row (global tb*24 + o)
      f32x4 acc = {0.f, 0.f, 0.f, 0.f};
#pragma unroll
      for (int kt = 0; kt < 3; ++kt) {
        int p = kt * 4 + q;
        int pp = (p < 9) ? p : 8;  // pad octets read a valid addr; B is 0 there
        int kh = pp / 3, kw = pp % 3;
        int ar = ((o + kh) * 82 + ct * 16 + m15 + kw) * 8;
        bf16x8 ah = *(const bf16x8*)&y0h[ar];
        bf16x8 al = *(const bf16x8*)&y0l[ar];
        acc = __builtin_amdgcn_mfma_f32_16x16x32_bf16(al, w1hf[kt], acc, 0, 0, 0);
        acc = __builtin_amdgcn_mfma_f32_16x16x32_bf16(ah, w1lf[kt], acc, 0, 0, 0);
        acc = __builtin_amdgcn_mfma_f32_16x16x32_bf16(ah, w1hf[kt], acc, 0, 0, 0);
      }
#pragma unroll
      for (int r = 0; r < 4; ++r)
        pmax[r] = fmaxf(pmax[r], fmaxf(acc[r] + b1c, 0.f));
    }
    int R = tb * 8 + pr;
    size_t base = (((size_t)b * 160 + R) * 40 + ct * 8 + q * 2) * 16 + m15;
    y2[base] = fmaxf(pmax[0], pmax[1]);
    y2[base + 16] = fmaxf(pmax[2], pmax[3]);
  }
}

// ======== conv2 + conv3 + pool via MFMA implicit GEMM, 2 blocks/CU ========
__global__ __launch_bounds__(512, 4) void conv23_mfma(
    const float* __restrict__ y2, const float* __restrict__ w2,
    const float* __restrict__ b2, const float* __restrict__ w3,
    const float* __restrict__ b3, short* __restrict__ xh,
    short* __restrict__ xl) {
  __shared__ __align__(16) short y2h[12 * 42 * 16], y2l[12 * 42 * 16];
  __shared__ __align__(16) short y3h[10 * 42 * 16], y3l[10 * 42 * 16];
  int b = blockIdx.x / 20, tb = blockIdx.x % 20;
  int tid = threadIdx.x;
  int wave = tid >> 6, lane = tid & 63, q = lane >> 4, m15 = lane & 15;
  int ci0 = (q & 1) * 8;

  // phase A: stage y2 band (rows 8tb-2..+9, cols -1..40) as split bf16
  for (int i = tid; i < 12 * 42 * 4; i += 512) {
    int ci4 = i & 3;
    int rest = i >> 2;
    int lc = rest % 42, r = rest / 42;
    int gr = tb * 8 - 2 + r, gc = lc - 1;
    float4 v = {0.f, 0.f, 0.f, 0.f};
    if (gr >= 0 && gr < 160 && gc >= 0 && gc < 40)
      v = *(const float4*)&y2[(((size_t)b * 160 + gr) * 40 + gc) * 16 + ci4 * 4];
    float f[4] = {v.x, v.y, v.z, v.w};
    s16x4 hv, lv;
#pragma unroll
    for (int e = 0; e < 4; ++e) {
      short hs = f2bf(f[e]);
      hv[e] = hs;
      lv[e] = f2bf(f[e] - bf2f(hs));
    }
    int idx = (r * 42 + lc) * 16 + ci4 * 4;
    *(s16x4*)&y2h[idx] = hv;
    *(s16x4*)&y2l[idx] = lv;
  }
  // zero y3 column halos (col 0 and 41, all 10 rows, 16 ch)
  for (int i = tid; i < 10 * 2 * 16; i += 512) {
    int rr = i / 32, sl = i % 32;
    int col = (sl >> 4) * 41, ch = sl & 15;
    y3h[(rr * 42 + col) * 16 + ch] = 0;
    y3l[(rr * 42 + col) * 16 + ch] = 0;
  }
  // conv2 weight fragments: B[k][n], n = m15 = out channel
  bf16x8 w2hf[5], w2lf[5];
#pragma unroll
  for (int kt = 0; kt < 5; ++kt) {
    int p = 2 * kt + (q >> 1);
    bf16x8 h, l;
#pragma unroll
    for (int e = 0; e < 8; ++e) {
      float w = (p < 9) ? w2[(m15 * 16 + ci0 + e) * 9 + p] : 0.f;
      short hs = f2bf(w);
      h[e] = hs;
      l[e] = f2bf(w - bf2f(hs));
    }
    w2hf[kt] = h; w2lf[kt] = l;
  }
  float b2c = b2[m15];
  __syncthreads();

  // phase B: conv2 -> y3 LDS (local rows 0..9 = global 8tb-1..8tb+8)
#pragma unroll 1
  for (int i = wave; i < 30; i += 8) {
    int rr = i / 3, ct = i % 3;
    f32x4 acc = {0.f, 0.f, 0.f, 0.f};
#pragma unroll
    for (int kt = 0; kt < 5; ++kt) {
      int p = 2 * kt + (q >> 1);
      int pp = (p < 9) ? p : 8;  // pad lanes read a valid addr; B is 0 there
      int kh = pp / 3, kw = pp % 3;
      int lc = min(ct * 16 + m15 + kw, 41);
      int ar = ((rr + kh) * 42 + lc) * 16 + ci0;
      bf16x8 ah = *(const bf16x8*)&y2h[ar];
      bf16x8 al = *(const bf16x8*)&y2l[ar];
      acc = __builtin_amdgcn_mfma_f32_16x16x32_bf16(al, w2hf[kt], acc, 0, 0, 0);
      acc = __builtin_amdgcn_mfma_f32_16x16x32_bf16(ah, w2lf[kt], acc, 0, 0, 0);
      acc = __builtin_amdgcn_mfma_f32_16x16x32_bf16(ah, w2hf[kt], acc, 0, 0, 0);
    }
    int grow = tb * 8 - 1 + rr;
    bool rowok = (grow >= 0 && grow < 160);
#pragma unroll
    for (int r = 0; r < 4; ++r) {
      int col = ct * 16 + q * 4 + r;  // C row = pixel col; C col = channel m15
      if (col < 40) {
        float v = rowok ? fmaxf(acc[r] + b2c, 0.f) : 0.f;
        short hs = f2bf(v);
        int di = (rr * 42 + 1 + col) * 16 + m15;
        y3h[di] = hs;
        y3l[di] = f2bf(v - bf2f(hs));
      }
    }
  }
  __syncthreads();

  // conv3 weight fragments: wave -> (pooled row pl, ch half nt, ct parity)
  int pl = wave >> 2, nt = (wave >> 1) & 1, sub = wave & 1;
  bf16x8 w3hf[5], w3lf[5];
#pragma unroll
  for (int kt = 0; kt < 5; ++kt) {
    int p = 2 * kt + (q >> 1);
    bf16x8 h, l;
#pragma unroll
    for (int e = 0; e < 8; ++e) {
      float w = (p < 9) ? w3[((nt * 16 + m15) * 16 + ci0 + e) * 9 + p] : 0.f;
      short hs = f2bf(w);
      h[e] = hs;
      l[e] = f2bf(w - bf2f(hs));
    }
    w3hf[kt] = h; w3lf[kt] = l;
  }
  float b3c = b3[nt * 16 + m15];

  // phase C: conv3 + relu + 4x2 pool, all in registers
#pragma unroll 1
  for (int ct = sub; ct < 3; ct += 2) {
    f32x4 pmax = {0.f, 0.f, 0.f, 0.f};
#pragma unroll
    for (int rr2 = 0; rr2 < 4; ++rr2) {
      int o = pl * 4 + rr2;  // conv3 local row; y3 local rows o..o+2
      f32x4 acc = {0.f, 0.f, 0.f, 0.f};
#pragma unroll
      for (int kt = 0; kt < 5; ++kt) {
        int p = 2 * kt + (q >> 1);
        int pp = (p < 9) ? p : 8;
        int kh = pp / 3, kw = pp % 3;
        int lc = min(ct * 16 + m15 + kw, 41);
        int ar = ((o + kh) * 42 + lc) * 16 + ci0;
        bf16x8 ah = *(const bf16x8*)&y3h[ar];
        bf16x8 al = *(const bf16x8*)&y3l[ar];
        acc = __builtin_amdgcn_mfma_f32_16x16x32_bf16(al, w3hf[kt], acc, 0, 0, 0);
        acc = __builtin_amdgcn_mfma_f32_16x16x32_bf16(ah, w3lf[kt], acc, 0, 0, 0);
        acc = __builtin_amdgcn_mfma_f32_16x16x32_bf16(ah, w3hf[kt], acc, 0, 0, 0);
      }
#pragma unroll
      for (int r = 0; r < 4; ++r) {
        float v = fmaxf(acc[r] + b3c, 0.f);
        pmax[r] = fmaxf(pmax[r], v);
      }
    }
    if (ct < 2 || q < 2) {
      int t = tb * 2 + pl;
      int wo = ct * 8 + q * 2;
      size_t base = (((size_t)t * 64 + b) * 20 + wo) * 32 + nt * 16 + m15;
      float v0 = fmaxf(pmax[0], pmax[1]);
      float v1 = fmaxf(pmax[2], pmax[3]);
      short s0 = f2bf(v0), s1 = f2bf(v1);
      xh[base] = s0;       xl[base] = f2bf(v0 - bf2f(s0));
      xh[base + 32] = s1;  xl[base + 32] = f2bf(v1 - bf2f(s1));
    }
  }
}

// ======== pre-split W_ih into bf16 hi/lo (once, not per gemm block) ========
__global__ __launch_bounds__(256) void split_w(
    const float* __restrict__ wf, const float* __restrict__ wb,
    short* __restrict__ Wh, short* __restrict__ Wl) {
  int i = blockIdx.x * 256 + threadIdx.x;  // octet index, 2*61440 total
  const float* src = (i < 61440) ? (wf + (size_t)i * 8)
                                 : (wb + (size_t)(i - 61440) * 8);
  bf16x8 h, l;
  split8(src, &h, &l);
  *(bf16x8*)&Wh[(size_t)i * 8] = h;
  *(bf16x8*)&Wl[(size_t)i * 8] = l;
}

// ======== gx GEMM: 512 threads (8 waves = 2/SIMD), reg-prefetch dbuf ======
__global__ __launch_bounds__(512, 2) void gemm_gx_mfma(
    const short* __restrict__ xh, const short* __restrict__ xl,
    const short* __restrict__ Wh, const short* __restrict__ Wl,
    const float* __restrict__ bih_f, const float* __restrict__ bih_b,
    const float* __restrict__ bhh_f, const float* __restrict__ bhh_b,
    float* __restrict__ gx) {
  __shared__ __align__(16) short Ah[2][4 * 128 * 8], Al[2][4 * 128 * 8];
  __shared__ __align__(16) short Bh[2][4 * 128 * 8], Bl[2][4 * 128 * 8];
  int bm = blockIdx.x * 128, bn = blockIdx.y * 128, dir = blockIdx.z;
  const short* Whd = Wh + (size_t)dir * WSZ_;
  const short* Wld = Wl + (size_t)dir * WSZ_;
  const float* bias = dir ? bih_b : bih_f;
  const float* bias2 = dir ? bhh_b : bhh_f;
  float* C = gx + (size_t)dir * (T_ * B_) * G3_;
  int tid = threadIdx.x;
  int wave = tid >> 6, lane = tid & 63, q = lane >> 4, n = lane & 15;
  int wm = (wave & 3) * 32, wn2 = (wave >> 2) * 64;
  f32x4 acc[2][4];
#pragma unroll
  for (int mi = 0; mi < 2; ++mi)
#pragma unroll
    for (int ni = 0; ni < 4; ++ni) acc[mi][ni] = (f32x4){0.f, 0.f, 0.f, 0.f};

  // staging map: thread -> (row = tid>>2, k-octet = tid&3)
  int srow = tid >> 2, sko = tid & 3;
  const short* xh0 = &xh[(size_t)(bm + srow) * IG_ + sko * 8];
  const short* xl0 = &xl[(size_t)(bm + srow) * IG_ + sko * 8];
  const short* wh0 = &Whd[(size_t)(bn + srow) * IG_ + sko * 8];
  const short* wl0 = &Wld[(size_t)(bn + srow) * IG_ + sko * 8];
  int sidx = (sko * 128 + srow) * 8;

  // prologue: stage k-tile 0 into buffer 0
  *(bf16x8*)&Ah[0][sidx] = *(const bf16x8*)xh0;
  *(bf16x8*)&Al[0][sidx] = *(const bf16x8*)xl0;
  *(bf16x8*)&Bh[0][sidx] = *(const bf16x8*)wh0;
  *(bf16x8*)&Bl[0][sidx] = *(const bf16x8*)wl0;
  __syncthreads();

  for (int t = 0; t < 20; ++t) {
    int cur = t & 1;
    bf16x8 ra, rl, rb, rm;
    if (t < 19) {
      int ko = (t + 1) * 32;
      ra = *(const bf16x8*)(xh0 + ko); rl = *(const bf16x8*)(xl0 + ko);
      rb = *(const bf16x8*)(wh0 + ko); rm = *(const bf16x8*)(wl0 + ko);
    }
    bf16x8 ah[2], al[2], bh[4], bl[4];
#pragma unroll
    for (int mi = 0; mi < 2; ++mi) {
      ah[mi] = *(const bf16x8*)&Ah[cur][(q * 128 + wm + mi * 16 + n) * 8];
      al[mi] = *(const bf16x8*)&Al[cur][(q * 128 + wm + mi * 16 + n) * 8];
    }
#pragma unroll
    for (int ni = 0; ni < 4; ++ni) {
      bh[ni] = *(const bf16x8*)&Bh[cur][(q * 128 + wn2 + ni * 16 + n) * 8];
      bl[ni] = *(const bf16x8*)&Bl[cur][(q * 128 + wn2 + ni * 16 + n) * 8];
    }
#pragma unroll
    for (int mi = 0; mi < 2; ++mi)
#pragma unroll
      for (int ni = 0; ni < 4; ++ni) {
        acc[mi][ni] = __builtin_amdgcn_mfma_f32_16x16x32_bf16(
            al[mi], bh[ni], acc[mi][ni], 0, 0, 0);
        acc[mi][ni] = __builtin_amdgcn_mfma_f32_16x16x32_bf16(
            ah[mi], bl[ni], acc[mi][ni], 0, 0, 0);
        acc[mi][ni] = __builtin_amdgcn_mfma_f32_16x16x32_bf16(
            ah[mi], bh[ni], acc[mi][ni], 0, 0, 0);
      }
    if (t < 19) {
      int nb = cur ^ 1;
      *(bf16x8*)&Ah[nb][sidx] = ra; *(bf16x8*)&Al[nb][sidx] = rl;
      *(bf16x8*)&Bh[nb][sidx] = rb; *(bf16x8*)&Bl[nb][sidx] = rm;
    }
    __syncthreads();
  }
#pragma unroll
  for (int mi = 0; mi < 2; ++mi)
#pragma unroll
    for (int ni = 0; ni < 4; ++ni)
#pragma unroll
      for (int r = 0; r < 4; ++r) {
        int row = bm + wm + mi * 16 + q * 4 + r;
        int col = bn + wn2 + ni * 16 + n;
        float bb = bias[col] + (col < 512 ? bias2[col] : 0.f);
        C[(size_t)row * G3_ + col] = acc[mi][ni][r] + bb;
      }
}

// ======== weight-stationary MFMA GRU (R8 structure + light barrier) ========
__global__ __launch_bounds__(1024) void gru_mfma(
    const float* __restrict__ gx,
    const float* __restrict__ whh_f, const float* __restrict__ whh_b,
    const float* __restrict__ bhh_f, const float* __restrict__ bhh_b,
    const float* __restrict__ h0, float* __restrict__ out) {
  __shared__ __align__(16) short wn[32 * 256 * 8];    // 128 KB [ch][j][8]
  __shared__ __align__(16) short hb[2][32 * 16 * 8];  // 2x8 KB [ch][b][8]
  int blk = blockIdx.x, dir = blk >> 2, mb = blk & 3;
  const float* Wh  = dir ? whh_b : whh_f;
  const float* bhh = dir ? bhh_b : bhh_f;
  int tid = threadIdx.x;
  int wave = tid >> 6, lane = tid & 63, q = lane >> 4, n = lane & 15;
  int jw = wave << 4;

  for (int idx = tid; idx < 256 * 32; idx += 1024) {
    int j = idx >> 5, ch = idx & 31;
    const float* src = Wh + (size_t)(512 + j) * HID_ + ch * 8;
    float4 u = *(const float4*)src, v = *(const float4*)(src + 4);
    short* d = &wn[(ch * 256 + j) * 8];
    d[0] = f2bf(u.x); d[1] = f2bf(u.y); d[2] = f2bf(u.z); d[3] = f2bf(u.w);
    d[4] = f2bf(v.x); d[5] = f2bf(v.y); d[6] = f2bf(v.z); d[7] = f2bf(v.w);
  }
  if (tid < 512) {
    int b = tid >> 5, ch = tid & 31;
    const float* src = h0 + (size_t)(dir * 64 + mb * 16 + b) * HID_ + ch * 8;
    float4 u = *(const float4*)src, v = *(const float4*)(src + 4);
    short* d = &hb[0][(ch * 16 + b) * 8];
    d[0] = f2bf(u.x); d[1] = f2bf(u.y); d[2] = f2bf(u.z); d[3] = f2bf(u.w);
    d[4] = f2bf(v.x); d[5] = f2bf(v.y); d[6] = f2bf(v.z); d[7] = f2bf(v.w);
  }
  bf16x8 Br[8], Bz[8];
#pragma unroll
  for (int kt = 0; kt < 8; ++kt) {
    const float* pr = Wh + (size_t)(jw + n) * HID_ + kt * 32 + q * 8;
    const float* pz = Wh + (size_t)(256 + jw + n) * HID_ + kt * 32 + q * 8;
    float4 u = *(const float4*)pr, v = *(const float4*)(pr + 4);
    Br[kt] = (bf16x8){f2bf(u.x), f2bf(u.y), f2bf(u.z), f2bf(u.w),
                      f2bf(v.x), f2bf(v.y), f2bf(v.z), f2bf(v.w)};
    float4 uz = *(const float4*)pz, vz = *(const float4*)(pz + 4);
    Bz[kt] = (bf16x8){f2bf(uz.x), f2bf(uz.y), f2bf(uz.z), f2bf(uz.w),
                      f2bf(vz.x), f2bf(vz.y), f2bf(vz.z), f2bf(vz.w)};
  }
  float hold[4];
#pragma unroll
  for (int r = 0; r < 4; ++r)
    hold[r] = h0[(size_t)(dir * 64 + mb * 16 + q * 4 + r) * HID_ + jw + n];
  float bh2 = bhh[512 + jw + n];  // r/z biases folded into gx by gemm
  int chc = (jw + n) >> 3, ce = (jw + n) & 7;

  // preload step 0's gx while weights stage
  float xr[4], xz[4], xn[4];
  {
    int t0 = dir ? (T_ - 1) : 0;
    const float* gxt = gx + ((size_t)(dir * T_ + t0) * B_ + mb * 16) * G3_;
#pragma unroll
    for (int r = 0; r < 4; ++r) {
      const float* gxb = gxt + (size_t)(q * 4 + r) * G3_ + jw + n;
      xr[r] = gxb[0]; xz[r] = gxb[256]; xn[r] = gxb[512];
    }
  }
  __syncthreads();

  for (int s = 0; s < T_; ++s) {
    int t = dir ? (T_ - 1 - s) : s;
    const short* hc = hb[s & 1];
    short* hx = hb[(s & 1) ^ 1];

    // prefetch next step's gx (step-independent data) — unconditional
    // clamped form: issues early, no exec-mask toggle (R17 showed the
    // guarded version delays load issue and costs ~8 us).
    float pxr[4], pxz[4], pxn[4];
    {
      int sn = (s + 1 < T_) ? s + 1 : s;  // clamp; last-iter loads unused
      int tn = dir ? (T_ - 1 - sn) : sn;
      const float* gxt = gx + ((size_t)(dir * T_ + tn) * B_ + mb * 16) * G3_;
#pragma unroll
      for (int r = 0; r < 4; ++r) {
        const float* gxb = gxt + (size_t)(q * 4 + r) * G3_ + jw + n;
        pxr[r] = gxb[0]; pxz[r] = gxb[256]; pxn[r] = gxb[512];
      }
    }

    f32x4 a0 = {0.f, 0.f, 0.f, 0.f}, a1 = a0, a2 = a0;
#pragma unroll
    for (int kt = 0; kt < 8; ++kt) {
      bf16x8 af = *(const bf16x8*)&hc[((kt * 4 + q) * 16 + n) * 8];
      bf16x8 bn = *(const bf16x8*)&wn[((kt * 4 + q) * 256 + jw + n) * 8];
      a0 = __builtin_amdgcn_mfma_f32_16x16x32_bf16(af, Br[kt], a0, 0, 0, 0);
      a1 = __builtin_amdgcn_mfma_f32_16x16x32_bf16(af, Bz[kt], a1, 0, 0, 0);
      a2 = __builtin_amdgcn_mfma_f32_16x16x32_bf16(af, bn, a2, 0, 0, 0);
    }
#pragma unroll
    for (int r = 0; r < 4; ++r) {
      float rg = sigm_(xr[r] + a0[r]);
      float zg = sigm_(xz[r] + a1[r]);
      float ng = tanh_(xn[r] + rg * (a2[r] + bh2));
      float hnew = (1.f - zg) * ng + zg * hold[r];
      hold[r] = hnew;
      int gb = mb * 16 + q * 4 + r;
      out[((size_t)gb * T_ + t) * (2 * HID_) + dir * HID_ + jw + n] = hnew;
      hx[(chc * 16 + q * 4 + r) * 8 + ce] = f2bf(hnew);
    }
#pragma unroll
    for (int r = 0; r < 4; ++r) {
      xr[r] = pxr[r]; xz[r] = pxz[r]; xn[r] = pxn[r];
    }
    // light barrier: order LDS hx writes only; leave global stores and the
    // gx prefetch loads in flight (compiler inserts vmcnt at first use).
    asm volatile("s_waitcnt lgkmcnt(0)\n\ts_barrier" ::: "memory");
  }
#pragma unroll
  for (int r = 0; r < 4; ++r)
    out[(size_t)OUT_MAIN_ + (size_t)(dir * 64 + mb * 16 + q * 4 + r) * HID_ + jw + n] = hold[r];
}

// ---------------- launch ----------------
extern "C" void kernel_launch(void* const* d_in, const int* in_sizes, int n_in,
                              void* d_out, int out_size, void* d_ws, size_t ws_size,
                              hipStream_t stream) {
  (void)in_sizes; (void)n_in; (void)out_size; (void)ws_size;
  const float* img    = (const float*)d_in[0];
  const float* hid0   = (const float*)d_in[1];
  const float* c0w    = (const float*)d_in[2];
  const float* c0b    = (const float*)d_in[3];
  const float* c1w    = (const float*)d_in[4];
  const float* c1b    = (const float*)d_in[5];
  const float* c2w    = (const float*)d_in[6];
  const float* c2b    = (const float*)d_in[7];
  const float* c3w    = (const float*)d_in[8];
  const float* c3b    = (const float*)d_in[9];
  const float* wih_f  = (const float*)d_in[10];
  const float* whh_f  = (const float*)d_in[11];
  const float* bih_f  = (const float*)d_in[12];
  const float* bhh_f  = (const float*)d_in[13];
  const float* wih_b  = (const float*)d_in[14];
  const float* whh_b  = (const float*)d_in[15];
  const float* bih_b  = (const float*)d_in[16];
  const float* bhh_b  = (const float*)d_in[17];
  float* out = (float*)d_out;

  float* wsf = (float*)d_ws;
  float* y2  = wsf;                         // 6,553,600 floats (dead after conv23)
  short* xh  = (short*)(wsf + 6553600);     // 1,638,400 shorts
  short* xl  = xh + 1638400;                // 1,638,400 shorts
  float* gx  = wsf + 8192000;               // 3,932,160 floats
  // W splits overlay the y2 region (y2 is dead once conv23 has run;
  // split_w is launched after conv23 because of this aliasing).
  short* Wh  = (short*)wsf;                 // 983,040 shorts
  short* Wl  = Wh + 983040;                 // 983,040 shorts

  conv01_mfma<<<64 * 20, 512, 0, stream>>>(img, c0w, c0b, c1w, c1b, y2);
  conv23_mfma<<<64 * 20, 512, 0, stream>>>(y2, c2w, c2b, c3w, c3b, xh, xl);
  split_w<<<480, 256, 0, stream>>>(wih_f, wih_b, Wh, Wl);
  gemm_gx_mfma<<<dim3(20, 6, 2), 512, 0, stream>>>(xh, xl, Wh, Wl, bih_f, bih_b,
                                                   bhh_f, bhh_b, gx);
  gru_mfma<<<8, 1024, 0, stream>>>(gx, whh_f, whh_b, bhh_f, bhh_b, hid0, out);
}